// Round 9
// baseline (207.524 us; speedup 1.0000x reference)
//
#include <hip/hip_runtime.h>
#include <math.h>

#define NN   1000
#define DD   128
#define CTXN 130
#define NEG_BIG (-1.0e30f)

// ============================================================================
// 4-dispatch pipeline, every emb-streaming kernel at B*8 = 2048 blocks:
//  k1p (B*8 x256): per-slice column sums (emb pass 1) + mask probe
//  kB' (B*8 x512): [mean+query+qproj per-block] -> compat -> local SM -> wembp
//                  (emb pass 2; slice LDS-resident for the outer product)
//  k4' (B*8 x512): [merge->heads->glimpse->g2 per-block] -> logits + LSE partials
//                  (emb pass 3)
//  k5  (B   x256): merge LSE partials -> out = logits - lse
// ws: meanp[B][1024] | wembp[B][8192] | stats[B][128] | logits[B][1024]
//     | lstats[B][16] | mflag
// ============================================================================

// ---------------- K1p: per-(b,s) partial column sums ----------------
__global__ __launch_bounds__(256, 8)
void k1_meanpart(const float* __restrict__ emb, const void* __restrict__ maskp,
                 float* __restrict__ meanp, int* __restrict__ mflag) {
    const int b = blockIdx.x >> 3, s = blockIdx.x & 7;
    const int t = threadIdx.x;
    const float* eb = emb + (size_t)b * (NN * DD);
    __shared__ __align__(16) float s_red[8 * 128];
    if (blockIdx.x == 0 && t == 0) {   // mask layout probe (int32: bytes 1 mod 4 all 0)
        const unsigned char* mb8 = (const unsigned char*)maskp;
        int any = 0;
        for (int k = 0; k < 64; ++k) any |= mb8[4 * k + 1];
        *mflag = (any == 0) ? 1 : 0;
    }
    const int c4 = t & 31, rg = t >> 5;
    float4 a = make_float4(0.f, 0.f, 0.f, 0.f);
    for (int nl = rg; nl < 125; nl += 8) {
        const float4 v = *(const float4*)(eb + (size_t)(s * 125 + nl) * DD + c4 * 4);
        a.x += v.x; a.y += v.y; a.z += v.z; a.w += v.w;
    }
    ((float4*)s_red)[rg * 32 + c4] = a;
    __syncthreads();
    if (t < 128) {
        float v = 0.f;
        #pragma unroll
        for (int g = 0; g < 8; ++g) v += s_red[g * 128 + t];
        meanp[(size_t)b * 1024 + s * 128 + t] = v;
    }
}

// ---------------- KB': per-block qproj prefix + compat + local SM + wembp ----------------
#define EST 132
__global__ __launch_bounds__(512, 4)
void kB_fused(const float* __restrict__ emb, const float* __restrict__ meanp,
              const float* __restrict__ stepc,
              const float* __restrict__ Wn, const float* __restrict__ Wf,
              const float* __restrict__ Ws,
              const void* __restrict__ maskp, const int* __restrict__ mflag,
              float* __restrict__ wembp, float* __restrict__ stats) {
    const int b = blockIdx.x >> 3, s = blockIdx.x & 7;
    const int t = threadIdx.x, w = t >> 6, lane = t & 63;
    const int rg = lane >> 4, cl = lane & 15;
    const float* eb = emb + (size_t)b * (NN * DD);
    __shared__ __align__(16) float s_qpT[1024];        // qproj [h][i]
    __shared__ __align__(16) float s_emb[125 * EST];   // 66 KB slice tile
    __shared__ __align__(16) float s_cp[128 * 8];      // compat -> p in place
    __shared__ float s_mean[128], s_q[128];
    __shared__ float s_scr[512];
    __shared__ float s_m[8], s_sum[8];
    // ---- prefix: mean -> query -> qproj (redundant per block, ~2 us) ----
    if (t < 128) {
        float v = 0.f;
        #pragma unroll
        for (int g = 0; g < 8; ++g) v += meanp[(size_t)b * 1024 + g * 128 + t];
        s_mean[t] = v * (1.0f / (float)NN);
    }
    __syncthreads();
    {   // query[d] = mean.Wf[:,d] + sc.Ws[:,d], 4-way split
        const int d = t & 127, p = t >> 7;
        float a = 0.f;
        for (int i = 32 * p; i < 32 * p + 32; ++i)
            a = fmaf(s_mean[i], Wf[i * DD + d], a);
        const float* scb = stepc + (size_t)b * CTXN;
        const int c0 = 32 * p, c1 = (p == 3) ? CTXN : 32 * p + 32;
        for (int c = c0; c < c1; ++c)
            a = fmaf(scb[c], Ws[c * DD + d], a);
        s_scr[p * 128 + d] = a;
    }
    __syncthreads();
    if (t < 128) s_q[t] = s_scr[t] + s_scr[128 + t] + s_scr[256 + t] + s_scr[384 + t];
    __syncthreads();
    {   // qproj[h][i] = 0.25 * sum_j Wn[i,16h+j] q[16h+j]
        const int i = t & 127, p = t >> 7;
        #pragma unroll
        for (int u = 0; u < 2; ++u) {
            const int h = p + 4 * u;
            float a = 0.f;
            #pragma unroll
            for (int j = 0; j < 16; ++j)
                a = fmaf(Wn[i * 384 + h * 16 + j], s_q[h * 16 + j], a);
            s_qpT[h * 128 + i] = a * 0.25f;
        }
    }
    __syncthreads();
    // ---- body: proven round-7/8 structure ----
    float4 qa[8], qb[8];
    #pragma unroll
    for (int h = 0; h < 8; ++h) {
        qa[h] = *(const float4*)&s_qpT[h * 128 + cl * 8];
        qb[h] = *(const float4*)&s_qpT[h * 128 + cl * 8 + 4];
    }
    const int use32 = *mflag;
    const unsigned char* mk8 = (const unsigned char*)maskp + (size_t)b * NN;
    const int* mk32 = (const int*)maskp + (size_t)b * NN;
    #pragma unroll
    for (int it = 0; it < 4; ++it) {
        const int r = w * 16 + it * 4 + rg;
        const int n = s * 125 + r;
        float acc[8] = {0.f,0.f,0.f,0.f,0.f,0.f,0.f,0.f};
        if (r < 125) {
            const float4 e0 = *(const float4*)(eb + (size_t)n * DD + cl * 8);
            const float4 e1 = *(const float4*)(eb + (size_t)n * DD + cl * 8 + 4);
            *(float4*)&s_emb[r * EST + cl * 8]     = e0;
            *(float4*)&s_emb[r * EST + cl * 8 + 4] = e1;
            #pragma unroll
            for (int h = 0; h < 8; ++h) {
                float a = e0.x * qa[h].x;
                a = fmaf(e0.y, qa[h].y, a);
                a = fmaf(e0.z, qa[h].z, a);
                a = fmaf(e0.w, qa[h].w, a);
                a = fmaf(e1.x, qb[h].x, a);
                a = fmaf(e1.y, qb[h].y, a);
                a = fmaf(e1.z, qb[h].z, a);
                a = fmaf(e1.w, qb[h].w, a);
                acc[h] = a;
            }
        }
        #pragma unroll
        for (int h = 0; h < 8; ++h) {
            acc[h] += __shfl_xor(acc[h], 1, 16);
            acc[h] += __shfl_xor(acc[h], 2, 16);
            acc[h] += __shfl_xor(acc[h], 4, 16);
            acc[h] += __shfl_xor(acc[h], 8, 16);
        }
        if (cl == 0 && r < 125) {
            const bool m = use32 ? (mk32[n] != 0) : (mk8[n] != 0);
            float4 o0, o1;
            if (m) { o0 = make_float4(NEG_BIG, NEG_BIG, NEG_BIG, NEG_BIG); o1 = o0; }
            else   { o0 = make_float4(acc[0], acc[1], acc[2], acc[3]);
                     o1 = make_float4(acc[4], acc[5], acc[6], acc[7]); }
            *(float4*)&s_cp[r * 8]     = o0;
            *(float4*)&s_cp[r * 8 + 4] = o1;
        }
    }
    __syncthreads();
    {   // local per-head max / raw sum (wave w = head w)
        float m = NEG_BIG;
        for (int r = lane; r < 125; r += 64) m = fmaxf(m, s_cp[r * 8 + w]);
        #pragma unroll
        for (int o = 32; o; o >>= 1) m = fmaxf(m, __shfl_xor(m, o, 64));
        float sum = 0.f;
        for (int r = lane; r < 125; r += 64) sum += expf(s_cp[r * 8 + w] - m);
        #pragma unroll
        for (int o = 32; o; o >>= 1) sum += __shfl_xor(sum, o, 64);
        if (lane == 0) { s_m[w] = m; s_sum[w] = sum; }
    }
    __syncthreads();
    for (int idx = t; idx < 1000; idx += 512)
        s_cp[idx] = expf(s_cp[idx] - s_m[idx & 7]);
    __syncthreads();
    {   // wembp from LDS tile: wave w owns cols [16w,16w+16), shfl(16/32) reduce
        const int col = w * 16 + cl;
        float acc[8] = {0.f,0.f,0.f,0.f,0.f,0.f,0.f,0.f};
        for (int r = rg; r < 125; r += 4) {
            const float  e  = s_emb[r * EST + col];
            const float4 p0 = *(const float4*)&s_cp[r * 8];
            const float4 p1 = *(const float4*)&s_cp[r * 8 + 4];
            acc[0] = fmaf(e, p0.x, acc[0]);
            acc[1] = fmaf(e, p0.y, acc[1]);
            acc[2] = fmaf(e, p0.z, acc[2]);
            acc[3] = fmaf(e, p0.w, acc[3]);
            acc[4] = fmaf(e, p1.x, acc[4]);
            acc[5] = fmaf(e, p1.y, acc[5]);
            acc[6] = fmaf(e, p1.z, acc[6]);
            acc[7] = fmaf(e, p1.w, acc[7]);
        }
        #pragma unroll
        for (int h = 0; h < 8; ++h) {
            acc[h] += __shfl_xor(acc[h], 16, 64);
            acc[h] += __shfl_xor(acc[h], 32, 64);
        }
        if (rg == 0) {
            #pragma unroll
            for (int h = 0; h < 8; ++h)
                wembp[(size_t)b * 8192 + s * 1024 + h * 128 + col] = acc[h];
        }
    }
    if (t < 8)        stats[(size_t)b * 128 + s * 16 + t] = s_m[t];
    else if (t < 16)  stats[(size_t)b * 128 + s * 16 + t] = s_sum[t - 8];
}

// ---------------- K4': per-block g2 prefix + logits + LSE partials ----------------
__global__ __launch_bounds__(512, 4)
void k4_logits(const float* __restrict__ emb, const float* __restrict__ wembp,
               const float* __restrict__ stats,
               const float* __restrict__ Wn, const float* __restrict__ Wo,
               const void* __restrict__ maskp, const int* __restrict__ mflag,
               float* __restrict__ logits, float* __restrict__ lstats) {
    const int b = blockIdx.x >> 3, s = blockIdx.x & 7;
    const int t = threadIdx.x, w = t >> 6, lane = t & 63;
    const int rg = lane >> 4, cl = lane & 15;
    const float* eb = emb + (size_t)b * (NN * DD);
    __shared__ float s_w[64];
    __shared__ float s_wemb[8 * 130];
    __shared__ float s_red[512];
    __shared__ float s_h[128], s_gl[128], s_g2[128];
    __shared__ float s_lg[128];
    // ---- prefix: merge -> wemb -> heads -> glimpse -> g2 (redundant per block) ----
    if (t < 8) {
        const int h = t;
        float m = NEG_BIG;
        #pragma unroll
        for (int ss = 0; ss < 8; ++ss) m = fmaxf(m, stats[(size_t)b * 128 + ss * 16 + h]);
        float den = 0.f;
        #pragma unroll
        for (int ss = 0; ss < 8; ++ss)
            den += stats[(size_t)b * 128 + ss * 16 + 8 + h] * expf(stats[(size_t)b * 128 + ss * 16 + h] - m);
        const float dinv = 1.0f / den;
        #pragma unroll
        for (int ss = 0; ss < 8; ++ss)
            s_w[ss * 8 + h] = expf(stats[(size_t)b * 128 + ss * 16 + h] - m) * dinv;
    }
    __syncthreads();
    for (int idx = t; idx < 1024; idx += 512) {
        const int h = idx >> 7, i = idx & 127;
        float v = 0.f;
        #pragma unroll
        for (int ss = 0; ss < 8; ++ss)
            v += wembp[(size_t)b * 8192 + ss * 1024 + idx] * s_w[ss * 8 + h];
        s_wemb[h * 130 + i] = v;
    }
    __syncthreads();
    {   // heads[j] = sum_i Wv[i,j] wemb[j>>4][i]
        const int j = t & 127, p = t >> 7;
        float a = 0.f;
        for (int i = 32 * p; i < 32 * p + 32; ++i)
            a = fmaf(Wn[i * 384 + 128 + j], s_wemb[(j >> 4) * 130 + i], a);
        s_red[p * 128 + j] = a;
    }
    __syncthreads();
    if (t < 128) s_h[t] = s_red[t] + s_red[128 + t] + s_red[256 + t] + s_red[384 + t];
    __syncthreads();
    {   // glimpse[d] = sum_j heads[j] Wo[j,d]
        const int d = t & 127, p = t >> 7;
        float a = 0.f;
        for (int j = 32 * p; j < 32 * p + 32; ++j)
            a = fmaf(s_h[j], Wo[j * DD + d], a);
        s_red[p * 128 + d] = a;
    }
    __syncthreads();
    if (t < 128) s_gl[t] = s_red[t] + s_red[128 + t] + s_red[256 + t] + s_red[384 + t];
    __syncthreads();
    {   // g2[i] = (1/sqrt(128)) sum_d Wl[i,d] glimpse[d]
        const int i = t & 127, p = t >> 7;
        float a = 0.f;
        for (int d = 32 * p; d < 32 * p + 32; ++d)
            a = fmaf(Wn[i * 384 + 256 + d], s_gl[d], a);
        s_red[p * 128 + i] = a;
    }
    __syncthreads();
    if (t < 128) {
        s_g2[t] = (s_red[t] + s_red[128 + t] + s_red[256 + t] + s_red[384 + t]) * 0.08838834764831845f;
        s_lg[t] = NEG_BIG;   // pad for the slice reduce (rows 125..127)
    }
    __syncthreads();
    // ---- logits stream: coalesced 4-rows-x-16-lanes ----
    {
        const float4 ga = *(const float4*)&s_g2[cl * 8];
        const float4 gb = *(const float4*)&s_g2[cl * 8 + 4];
        const int use32 = *mflag;
        const unsigned char* mk8 = (const unsigned char*)maskp + (size_t)b * NN;
        const int* mk32 = (const int*)maskp + (size_t)b * NN;
        #pragma unroll
        for (int it = 0; it < 4; ++it) {
            const int r = w * 16 + it * 4 + rg;
            const int n = s * 125 + r;
            float a = 0.f;
            if (r < 125) {
                const float4 e0 = *(const float4*)(eb + (size_t)n * DD + cl * 8);
                const float4 e1 = *(const float4*)(eb + (size_t)n * DD + cl * 8 + 4);
                a = e0.x * ga.x;
                a = fmaf(e0.y, ga.y, a);
                a = fmaf(e0.z, ga.z, a);
                a = fmaf(e0.w, ga.w, a);
                a = fmaf(e1.x, gb.x, a);
                a = fmaf(e1.y, gb.y, a);
                a = fmaf(e1.z, gb.z, a);
                a = fmaf(e1.w, gb.w, a);
            }
            a += __shfl_xor(a, 1, 16);
            a += __shfl_xor(a, 2, 16);
            a += __shfl_xor(a, 4, 16);
            a += __shfl_xor(a, 8, 16);
            if (cl == 0 && r < 125) {
                const bool m = use32 ? (mk32[n] != 0) : (mk8[n] != 0);
                const float v = m ? NEG_BIG : 10.0f * tanhf(a);
                s_lg[r] = v;
                logits[(size_t)b * 1024 + n] = v;
            }
        }
    }
    __syncthreads();
    // ---- slice LSE partials (wave 0) ----
    if (w == 0) {
        float m = NEG_BIG;
        for (int r = lane; r < 125; r += 64) m = fmaxf(m, s_lg[r]);
        #pragma unroll
        for (int o = 32; o; o >>= 1) m = fmaxf(m, __shfl_xor(m, o, 64));
        float sum = 0.f;
        for (int r = lane; r < 125; r += 64) sum += expf(s_lg[r] - m);
        #pragma unroll
        for (int o = 32; o; o >>= 1) sum += __shfl_xor(sum, o, 64);
        if (lane == 0) {
            lstats[(size_t)b * 16 + s * 2]     = m;
            lstats[(size_t)b * 16 + s * 2 + 1] = sum;
        }
    }
}

// ---------------- K5: merge LSE partials -> out ----------------
__global__ __launch_bounds__(256, 8)
void k5_norm(const float* __restrict__ logits, const float* __restrict__ lstats,
             float* __restrict__ out) {
    const int b = blockIdx.x, t = threadIdx.x;
    float m = NEG_BIG;
    #pragma unroll
    for (int s = 0; s < 8; ++s) m = fmaxf(m, lstats[(size_t)b * 16 + s * 2]);
    float den = 0.f;
    #pragma unroll
    for (int s = 0; s < 8; ++s)
        den += lstats[(size_t)b * 16 + s * 2 + 1] * expf(lstats[(size_t)b * 16 + s * 2] - m);
    const float lse = m + logf(den);
    for (int n = t; n < NN; n += 256)
        out[(size_t)b * NN + n] = logits[(size_t)b * 1024 + n] - lse;
}

extern "C" void kernel_launch(void* const* d_in, const int* in_sizes, int n_in,
                              void* d_out, int out_size, void* d_ws, size_t ws_size,
                              hipStream_t stream) {
    const float* emb   = (const float*)d_in[0];
    const float* stepc = (const float*)d_in[1];
    const void*  mask  = (const void*)d_in[2];
    const float* Wn = (const float*)d_in[3];
    const float* Wf = (const float*)d_in[4];
    const float* Ws = (const float*)d_in[5];
    const float* Wo = (const float*)d_in[6];
    float* out = (float*)d_out;
    const int B = in_sizes[0] / (NN * DD);  // 256

    float* wsf = (float*)d_ws;
    const size_t n_meanp = (size_t)B * 1024;
    const size_t n_wembp = (size_t)B * 8192;
    const size_t n_stats = (size_t)B * 128;
    const size_t n_logit = (size_t)B * 1024;
    const size_t n_lst   = (size_t)B * 16;

    float* meanp  = wsf;
    float* wembp  = meanp + n_meanp;
    float* stats  = wembp + n_wembp;
    float* logits = stats + n_stats;
    float* lstats = logits + n_logit;
    int*   mflag  = (int*)(lstats + n_lst);

    k1_meanpart<<<B * 8, 256, 0, stream>>>(emb, mask, meanp, mflag);
    kB_fused   <<<B * 8, 512, 0, stream>>>(emb, meanp, stepc, Wn, Wf, Ws, mask, mflag, wembp, stats);
    k4_logits  <<<B * 8, 512, 0, stream>>>(emb, wembp, stats, Wn, Wo, mask, mflag, logits, lstats);
    k5_norm    <<<B,     256, 0, stream>>>(logits, lstats, out);
}

// Round 10
// 131.800 us; speedup vs baseline: 1.5745x; 1.5745x over previous
//
#include <hip/hip_runtime.h>
#include <math.h>

#define NN   1000
#define DD   128
#define CTXN 130
#define NEG_BIG (-1.0e30f)

// ============================================================================
// 3-dispatch pipeline:
//  k1_fused (B x1024) : emb -> mean -> query -> qproj[h][i] (+mask probe)
//  kB       (B*16x512): compat -> slice-local softmax -> wembp  [4 blk/CU]
//  k4_fused (B x1024) : merge -> heads -> glimpse -> g2 -> logits -> log_softmax
// ws: qpt[B][1024] | wembp[B][16][1024] | stats[B][16][16] | mflag
// ============================================================================

// ---------------- K1': mean + query + qproj, one block per batch ----------------
__global__ __launch_bounds__(1024, 4)
void k1_fused(const float* __restrict__ emb, const float* __restrict__ stepc,
              const void* __restrict__ maskp,
              const float* __restrict__ Wn, const float* __restrict__ Wf,
              const float* __restrict__ Ws,
              float* __restrict__ qpt, int* __restrict__ mflag) {
    const int b = blockIdx.x, t = threadIdx.x;
    const float* eb = emb + (size_t)b * (NN * DD);
    __shared__ __align__(16) float S[4096];
    __shared__ float s_mean[128], s_q[128];
    if (b == 0 && t == 0) {   // mask layout probe (int32: bytes 1 mod 4 all 0)
        const unsigned char* mb8 = (const unsigned char*)maskp;
        int any = 0;
        for (int k = 0; k < 64; ++k) any |= mb8[4 * k + 1];
        *mflag = (any == 0) ? 1 : 0;
    }
    {   // mean: 32 row-groups x 32 float4-columns
        const int c4 = t & 31, g = t >> 5;
        float4 a = make_float4(0.f, 0.f, 0.f, 0.f);
        for (int r = g; r < NN; r += 32) {
            const float4 v = *(const float4*)(eb + (size_t)r * DD + c4 * 4);
            a.x += v.x; a.y += v.y; a.z += v.z; a.w += v.w;
        }
        ((float4*)S)[g * 32 + c4] = a;
    }
    __syncthreads();
    if (t < 128) {
        float v = 0.f;
        #pragma unroll
        for (int g = 0; g < 32; ++g) v += S[g * 128 + t];
        s_mean[t] = v * (1.0f / (float)NN);
    }
    __syncthreads();
    {   // query[d] = mean.Wf[:,d] + sc.Ws[:,d], 8-way split
        const int d = t & 127, p = t >> 7;
        float a = 0.f;
        for (int i = 16 * p; i < 16 * p + 16; ++i)
            a = fmaf(s_mean[i], Wf[i * DD + d], a);
        const float* scb = stepc + (size_t)b * CTXN;
        const int c0 = 16 * p, c1 = (p == 7) ? CTXN : 16 * p + 16;
        for (int c = c0; c < c1; ++c)
            a = fmaf(scb[c], Ws[c * DD + d], a);
        S[p * 128 + d] = a;
    }
    __syncthreads();
    if (t < 128) {
        float v = 0.f;
        #pragma unroll
        for (int p = 0; p < 8; ++p) v += S[p * 128 + t];
        s_q[t] = v;
    }
    __syncthreads();
    {   // qproj one-shot: thread (i = t&127, h = t>>7)
        const int i = t & 127, h = t >> 7;
        float a = 0.f;
        #pragma unroll
        for (int j = 0; j < 16; ++j)
            a = fmaf(Wn[i * 384 + h * 16 + j], s_q[h * 16 + j], a);
        qpt[(size_t)b * 1024 + h * 128 + i] = a * 0.25f;  // 1/sqrt(16)
    }
}

// ---------------- KB: compat + local softmax + wembp, 16 slices, 4 blk/CU ----------------
#define EST 136   // row stride: step-4 read bank = (8*rg + cl + 16w) % 32 -> 2-way (free)
__global__ __launch_bounds__(512, 4)
void kB_fused(const float* __restrict__ emb, const float* __restrict__ qpt,
              const void* __restrict__ maskp, const int* __restrict__ mflag,
              float* __restrict__ wembp, float* __restrict__ stats) {
    const int b = blockIdx.x >> 4, s = blockIdx.x & 15;
    const int t = threadIdx.x, w = t >> 6, lane = t & 63;
    const int rg = lane >> 4, cl = lane & 15;
    const int r0 = s * 63;
    const int nrows = (s == 15) ? (NN - 15 * 63) : 63;   // 55 for last slice
    const float* eb = emb + (size_t)b * (NN * DD);
    __shared__ __align__(16) float s_qpT[1024];          // 4 KB
    __shared__ __align__(16) float s_emb[63 * EST];      // 33.5 KB
    __shared__ __align__(16) float s_cp[64 * 8];         // 2 KB, compat -> p
    __shared__ float s_m[8], s_sum[8];
    for (int i = t; i < 1024; i += 512) s_qpT[i] = qpt[(size_t)b * 1024 + i];
    __syncthreads();
    float4 qa[8], qb[8];   // qproj cols cl*8..cl*8+7, all heads (64 VGPR)
    #pragma unroll
    for (int h = 0; h < 8; ++h) {
        qa[h] = *(const float4*)&s_qpT[h * 128 + cl * 8];
        qb[h] = *(const float4*)&s_qpT[h * 128 + cl * 8 + 4];
    }
    const int use32 = *mflag;
    const unsigned char* mk8 = (const unsigned char*)maskp + (size_t)b * NN;
    const int* mk32 = (const int*)maskp + (size_t)b * NN;
    // ---- step 1: compat + tee slice into LDS (wave w owns rows [8w, 8w+8)) ----
    #pragma unroll
    for (int it = 0; it < 2; ++it) {
        const int r = w * 8 + it * 4 + rg;    // 0..63
        const int n = r0 + r;
        float acc[8] = {0.f,0.f,0.f,0.f,0.f,0.f,0.f,0.f};
        if (r < nrows) {
            const float4 e0 = *(const float4*)(eb + (size_t)n * DD + cl * 8);
            const float4 e1 = *(const float4*)(eb + (size_t)n * DD + cl * 8 + 4);
            *(float4*)&s_emb[r * EST + cl * 8]     = e0;
            *(float4*)&s_emb[r * EST + cl * 8 + 4] = e1;
            #pragma unroll
            for (int h = 0; h < 8; ++h) {
                float a = e0.x * qa[h].x;
                a = fmaf(e0.y, qa[h].y, a);
                a = fmaf(e0.z, qa[h].z, a);
                a = fmaf(e0.w, qa[h].w, a);
                a = fmaf(e1.x, qb[h].x, a);
                a = fmaf(e1.y, qb[h].y, a);
                a = fmaf(e1.z, qb[h].z, a);
                a = fmaf(e1.w, qb[h].w, a);
                acc[h] = a;
            }
        }
        #pragma unroll
        for (int h = 0; h < 8; ++h) {
            acc[h] += __shfl_xor(acc[h], 1, 16);
            acc[h] += __shfl_xor(acc[h], 2, 16);
            acc[h] += __shfl_xor(acc[h], 4, 16);
            acc[h] += __shfl_xor(acc[h], 8, 16);
        }
        if (cl == 0 && r < nrows) {
            const bool m = use32 ? (mk32[n] != 0) : (mk8[n] != 0);
            float4 o0, o1;
            if (m) { o0 = make_float4(NEG_BIG, NEG_BIG, NEG_BIG, NEG_BIG); o1 = o0; }
            else   { o0 = make_float4(acc[0], acc[1], acc[2], acc[3]);
                     o1 = make_float4(acc[4], acc[5], acc[6], acc[7]); }
            *(float4*)&s_cp[r * 8]     = o0;
            *(float4*)&s_cp[r * 8 + 4] = o1;
        }
    }
    __syncthreads();
    {   // ---- step 2: local per-head max / raw sum (wave w = head w) ----
        float m = NEG_BIG;
        if (lane < nrows) m = s_cp[lane * 8 + w];
        #pragma unroll
        for (int o = 32; o; o >>= 1) m = fmaxf(m, __shfl_xor(m, o, 64));
        float sum = (lane < nrows) ? expf(s_cp[lane * 8 + w] - m) : 0.f;
        #pragma unroll
        for (int o = 32; o; o >>= 1) sum += __shfl_xor(sum, o, 64);
        if (lane == 0) { s_m[w] = m; s_sum[w] = sum; }
    }
    __syncthreads();
    // ---- step 3: unnormalized p in place ----
    for (int idx = t; idx < nrows * 8; idx += 512)
        s_cp[idx] = expf(s_cp[idx] - s_m[idx & 7]);
    __syncthreads();
    {   // ---- step 4: wembp from LDS tile (wave w owns cols [16w,16w+16)) ----
        const int col = w * 16 + cl;
        float acc[8] = {0.f,0.f,0.f,0.f,0.f,0.f,0.f,0.f};
        for (int r = rg; r < nrows; r += 4) {
            const float  e  = s_emb[r * EST + col];
            const float4 p0 = *(const float4*)&s_cp[r * 8];
            const float4 p1 = *(const float4*)&s_cp[r * 8 + 4];
            acc[0] = fmaf(e, p0.x, acc[0]);
            acc[1] = fmaf(e, p0.y, acc[1]);
            acc[2] = fmaf(e, p0.z, acc[2]);
            acc[3] = fmaf(e, p0.w, acc[3]);
            acc[4] = fmaf(e, p1.x, acc[4]);
            acc[5] = fmaf(e, p1.y, acc[5]);
            acc[6] = fmaf(e, p1.z, acc[6]);
            acc[7] = fmaf(e, p1.w, acc[7]);
        }
        #pragma unroll
        for (int h = 0; h < 8; ++h) {
            acc[h] += __shfl_xor(acc[h], 16, 64);
            acc[h] += __shfl_xor(acc[h], 32, 64);
        }
        if (rg == 0) {
            #pragma unroll
            for (int h = 0; h < 8; ++h)
                wembp[(size_t)b * 16384 + s * 1024 + h * 128 + col] = acc[h];
        }
    }
    if (t < 8)        stats[(size_t)b * 256 + s * 16 + t] = s_m[t];
    else if (t < 16)  stats[(size_t)b * 256 + s * 16 + t] = s_sum[t - 8];
}

// ---------------- K4': merge -> g2 -> logits -> log_softmax, one block per batch ----------------
__global__ __launch_bounds__(1024, 4)
void k4_fused(const float* __restrict__ emb, const float* __restrict__ wembp,
              const float* __restrict__ stats,
              const float* __restrict__ Wn, const float* __restrict__ Wo,
              const void* __restrict__ maskp, const int* __restrict__ mflag,
              float* __restrict__ out) {
    const int b = blockIdx.x, t = threadIdx.x;
    const int w = t >> 6, lane = t & 63;
    const int rg = lane >> 4, cl = lane & 15;
    const float* eb = emb + (size_t)b * (NN * DD);
    __shared__ float s_w[128];           // [s][h], 16 slices
    __shared__ float s_wemb[8 * 130];
    __shared__ __align__(16) float s_red[1024];
    __shared__ float s_h[128], s_gl[128], s_g2[128];
    __shared__ float s_logits[1000];
    __shared__ float s_r2[32];
    __shared__ float s_lse;
    // ---- merge weights over 16 slices ----
    if (t < 8) {
        const int h = t;
        float m = NEG_BIG;
        #pragma unroll
        for (int ss = 0; ss < 16; ++ss) m = fmaxf(m, stats[(size_t)b * 256 + ss * 16 + h]);
        float den = 0.f;
        #pragma unroll
        for (int ss = 0; ss < 16; ++ss)
            den += stats[(size_t)b * 256 + ss * 16 + 8 + h] * expf(stats[(size_t)b * 256 + ss * 16 + h] - m);
        const float dinv = 1.0f / den;
        #pragma unroll
        for (int ss = 0; ss < 16; ++ss)
            s_w[ss * 8 + h] = expf(stats[(size_t)b * 256 + ss * 16 + h] - m) * dinv;
    }
    __syncthreads();
    {   // wemb[h][i]: one shot (t = h*128+i)
        const int h = t >> 7, i = t & 127;
        float v = 0.f;
        #pragma unroll
        for (int ss = 0; ss < 16; ++ss)
            v += wembp[(size_t)b * 16384 + ss * 1024 + t] * s_w[ss * 8 + h];
        s_wemb[h * 130 + i] = v;
    }
    __syncthreads();
    {   // heads[j] = sum_i Wv[i,j] wemb[j>>4][i], 8-way i-split
        const int j = t & 127, p = t >> 7;
        float a = 0.f;
        for (int i = 16 * p; i < 16 * p + 16; ++i)
            a = fmaf(Wn[i * 384 + 128 + j], s_wemb[(j >> 4) * 130 + i], a);
        s_red[p * 128 + j] = a;
    }
    __syncthreads();
    if (t < 128) {
        float v = 0.f;
        #pragma unroll
        for (int p = 0; p < 8; ++p) v += s_red[p * 128 + t];
        s_h[t] = v;
    }
    __syncthreads();
    {   // glimpse[d] = sum_j heads[j] Wo[j,d]
        const int d = t & 127, p = t >> 7;
        float a = 0.f;
        for (int j = 16 * p; j < 16 * p + 16; ++j)
            a = fmaf(s_h[j], Wo[j * DD + d], a);
        s_red[p * 128 + d] = a;
    }
    __syncthreads();
    if (t < 128) {
        float v = 0.f;
        #pragma unroll
        for (int p = 0; p < 8; ++p) v += s_red[p * 128 + t];
        s_gl[t] = v;
    }
    __syncthreads();
    {   // g2[i] = (1/sqrt(128)) sum_d Wl[i,d] glimpse[d]
        const int i = t & 127, p = t >> 7;
        float a = 0.f;
        for (int d = 16 * p; d < 16 * p + 16; ++d)
            a = fmaf(Wn[i * 384 + 256 + d], s_gl[d], a);
        s_red[p * 128 + i] = a;
    }
    __syncthreads();
    if (t < 128) {
        float v = 0.f;
        #pragma unroll
        for (int p = 0; p < 8; ++p) v += s_red[p * 128 + t];
        s_g2[t] = v * 0.08838834764831845f;
    }
    __syncthreads();
    // ---- logits: 16 waves x 4-rows-x-16-lanes, coalesced ----
    {
        const float4 ga = *(const float4*)&s_g2[cl * 8];
        const float4 gb = *(const float4*)&s_g2[cl * 8 + 4];
        const int use32 = *mflag;
        const unsigned char* mk8 = (const unsigned char*)maskp + (size_t)b * NN;
        const int* mk32 = (const int*)maskp + (size_t)b * NN;
        for (int it = 0; it < 16; ++it) {
            const int n = it * 64 + w * 4 + rg;   // 0..1023
            float a = 0.f;
            if (n < NN) {
                const float4 e0 = *(const float4*)(eb + (size_t)n * DD + cl * 8);
                const float4 e1 = *(const float4*)(eb + (size_t)n * DD + cl * 8 + 4);
                a = e0.x * ga.x;
                a = fmaf(e0.y, ga.y, a);
                a = fmaf(e0.z, ga.z, a);
                a = fmaf(e0.w, ga.w, a);
                a = fmaf(e1.x, gb.x, a);
                a = fmaf(e1.y, gb.y, a);
                a = fmaf(e1.z, gb.z, a);
                a = fmaf(e1.w, gb.w, a);
            }
            a += __shfl_xor(a, 1, 16);
            a += __shfl_xor(a, 2, 16);
            a += __shfl_xor(a, 4, 16);
            a += __shfl_xor(a, 8, 16);
            if (cl == 0 && n < NN) {
                const bool m = use32 ? (mk32[n] != 0) : (mk8[n] != 0);
                s_logits[n] = m ? NEG_BIG : 10.0f * tanhf(a);
            }
        }
    }
    __syncthreads();
    // ---- log_softmax ----
    {
        float m = NEG_BIG;
        if (t < NN) m = s_logits[t];
        #pragma unroll
        for (int o = 32; o; o >>= 1) m = fmaxf(m, __shfl_xor(m, o, 64));
        if (lane == 0) s_r2[w] = m;
        __syncthreads();
        if (t == 0) {
            float mm = s_r2[0];
            #pragma unroll
            for (int i = 1; i < 16; ++i) mm = fmaxf(mm, s_r2[i]);
            s_r2[16] = mm;
        }
        __syncthreads();
        const float mb = s_r2[16];
        float sum = (t < NN) ? expf(s_logits[t] - mb) : 0.f;
        #pragma unroll
        for (int o = 32; o; o >>= 1) sum += __shfl_xor(sum, o, 64);
        __syncthreads();
        if (lane == 0) s_r2[w] = sum;
        __syncthreads();
        if (t == 0) {
            float ss = 0.f;
            #pragma unroll
            for (int i = 0; i < 16; ++i) ss += s_r2[i];
            s_lse = mb + logf(ss);
        }
        __syncthreads();
        if (t < NN) out[(size_t)b * NN + t] = s_logits[t] - s_lse;
    }
}

extern "C" void kernel_launch(void* const* d_in, const int* in_sizes, int n_in,
                              void* d_out, int out_size, void* d_ws, size_t ws_size,
                              hipStream_t stream) {
    const float* emb   = (const float*)d_in[0];
    const float* stepc = (const float*)d_in[1];
    const void*  mask  = (const void*)d_in[2];
    const float* Wn = (const float*)d_in[3];
    const float* Wf = (const float*)d_in[4];
    const float* Ws = (const float*)d_in[5];
    const float* Wo = (const float*)d_in[6];
    float* out = (float*)d_out;
    const int B = in_sizes[0] / (NN * DD);  // 256

    float* wsf = (float*)d_ws;
    const size_t n_qpt   = (size_t)B * 1024;
    const size_t n_wembp = (size_t)B * 16384;
    const size_t n_stats = (size_t)B * 256;

    float* qpt   = wsf;
    float* wembp = qpt + n_qpt;
    float* stats = wembp + n_wembp;
    int*   mflag = (int*)(stats + n_stats);

    k1_fused<<<B,      1024, 0, stream>>>(emb, stepc, mask, Wn, Wf, Ws, qpt, mflag);
    kB_fused<<<B * 16, 512,  0, stream>>>(emb, qpt, mask, mflag, wembp, stats);
    k4_fused<<<B,      1024, 0, stream>>>(emb, wembp, stats, Wn, Wo, mask, mflag, out);
}